// Round 2
// baseline (491.369 us; speedup 1.0000x reference)
//
#include <hip/hip_runtime.h>
#include <cstddef>

#define BATCH 16384
#define IN_F  4096
#define OUT_F 4096

// ---------------- ws layout (bytes) ----------------
// [0, 1MB)          : partial[BATCH][4 parts][4]  float  (written by k_project)
// [1MB, 1MB+64KB)   : ain_tab[4096][4]            float  (A_in rows)
// [+64KB, +128KB)   : e_tab[4096][4]              float  (A_out @ CP rows)
// [+128KB, +144KB)  : bias_tab[4096]              float
#define WS_PARTIAL_OFF 0
#define WS_AIN_OFF     (1u << 20)
#define WS_E_OFF       (WS_AIN_OFF + (64u << 10))
#define WS_BIAS_OFF    (WS_E_OFF + (64u << 10))

// Keys cubic convolution, a = -0.75 (torch bicubic), align_corners=True.
__device__ __forceinline__ float cub_inner(float s) {
    return (1.25f * s - 2.25f) * s * s + 1.0f;
}
__device__ __forceinline__ float cub_outer(float s) {
    return ((-0.75f * s + 3.75f) * s - 6.0f) * s + 3.0f;
}

__device__ __forceinline__ void cubic_row(int i, float& a0, float& a1, float& a2, float& a3) {
    const float inv = 3.0f / 4095.0f;
    const float xi = (float)i * inv;
    const float x0 = floorf(xi);
    const float t  = xi - x0;
    const int   c  = (int)x0;
    const float w0 = cub_outer(t + 1.0f);
    const float w1 = cub_inner(t);
    const float w2 = cub_inner(1.0f - t);
    const float w3 = cub_outer(2.0f - t);
    if (c == 0)      { a0 = w0 + w1; a1 = w2;   a2 = w3;   a3 = 0.0f; }
    else if (c == 1) { a0 = w0;      a1 = w1;   a2 = w2;   a3 = w3; }
    else if (c == 2) { a0 = 0.0f;    a1 = w0;   a2 = w1;   a3 = w2 + w3; }
    else             { a0 = 0.0f;    a1 = 0.0f; a2 = w0;   a3 = w1 + w2 + w3; }
}

// ---------------- init: build tables ----------------
__global__ __launch_bounds__(256) void k_init(const float* __restrict__ cp,
                                              const float* __restrict__ bcp,
                                              float* __restrict__ ws) {
    const int i = blockIdx.x * 256 + threadIdx.x;   // 0..4095
    float a0, a1, a2, a3;
    cubic_row(i, a0, a1, a2, a3);

    float4* ain  = (float4*)((char*)ws + WS_AIN_OFF);
    float4* etab = (float4*)((char*)ws + WS_E_OFF);
    float*  btab = (float*)((char*)ws + WS_BIAS_OFF);

    ain[i] = make_float4(a0, a1, a2, a3);

    float4 e;
    e.x = a0 * cp[0]  + a1 * cp[4]  + a2 * cp[8]  + a3 * cp[12];
    e.y = a0 * cp[1]  + a1 * cp[5]  + a2 * cp[9]  + a3 * cp[13];
    e.z = a0 * cp[2]  + a1 * cp[6]  + a2 * cp[10] + a3 * cp[14];
    e.w = a0 * cp[3]  + a1 * cp[7]  + a2 * cp[11] + a3 * cp[15];
    etab[i] = e;

    // linear bias interp, align_corners=True, 4 control points
    const float xb = (float)i * (3.0f / 4095.0f);
    const float lo = floorf(xb);
    const float tb = xb - lo;
    const int   l  = (int)lo;
    const float blo = bcp[l < 3 ? l : 3];
    const float bhi = bcp[(l + 1) < 3 ? (l + 1) : 3];
    btab[i] = (1.0f - tb) * blo + tb * bhi;
}

// ---------------- k_project ----------------
// Grid: 2048 blocks x 256 threads. Block covers 8 rows.
// Wave w owns column-part w (1024 cols). Lane owns 16 strided columns; its 64
// weight floats load ONCE, then 8 rows of 64 FMAs + shfl-reduce each.
// Per-wave partial quad -> ws (no cross-wave barrier).
__global__ __launch_bounds__(256) void k_project(const float* __restrict__ x,
                                                 float* __restrict__ ws) {
    const int tid  = threadIdx.x;
    const int w    = tid >> 6;        // wave id = column part, 0..3
    const int lane = tid & 63;
    const int r0   = blockIdx.x * 8;

    const float4* ain = (const float4*)((char*)ws + WS_AIN_OFF);
    float4* partial   = (float4*)((char*)ws + WS_PARTIAL_OFF);

    // float4-group base indices within a row (in float4 units)
    int c4[4];
    float4 wq[4][4];   // [group][element] weight quads
#pragma unroll
    for (int g = 0; g < 4; ++g) {
        c4[g] = 256 * w + 64 * g + lane;
#pragma unroll
        for (int e = 0; e < 4; ++e)
            wq[g][e] = ain[4 * c4[g] + e];
    }

    for (int r = 0; r < 8; ++r) {
        const int row = r0 + r;
        const float4* xr = (const float4*)(x + (size_t)row * IN_F);
        float acc0 = 0.f, acc1 = 0.f, acc2 = 0.f, acc3 = 0.f;
#pragma unroll
        for (int g = 0; g < 4; ++g) {
            const float4 xv = xr[c4[g]];
            acc0 += wq[g][0].x * xv.x; acc1 += wq[g][0].y * xv.x;
            acc2 += wq[g][0].z * xv.x; acc3 += wq[g][0].w * xv.x;
            acc0 += wq[g][1].x * xv.y; acc1 += wq[g][1].y * xv.y;
            acc2 += wq[g][1].z * xv.y; acc3 += wq[g][1].w * xv.y;
            acc0 += wq[g][2].x * xv.z; acc1 += wq[g][2].y * xv.z;
            acc2 += wq[g][2].z * xv.z; acc3 += wq[g][2].w * xv.z;
            acc0 += wq[g][3].x * xv.w; acc1 += wq[g][3].y * xv.w;
            acc2 += wq[g][3].z * xv.w; acc3 += wq[g][3].w * xv.w;
        }
#pragma unroll
        for (int m = 32; m > 0; m >>= 1) {
            acc0 += __shfl_xor(acc0, m);
            acc1 += __shfl_xor(acc1, m);
            acc2 += __shfl_xor(acc2, m);
            acc3 += __shfl_xor(acc3, m);
        }
        if (lane == 0)
            partial[row * 4 + w] = make_float4(acc0, acc1, acc2, acc3);
    }
}

// ---------------- k_expand ----------------
// Grid: (4, 512) x 256 threads. Block covers 1024 outputs x 32 rows.
// Partials for the 32 rows staged+combined into LDS once (one barrier).
__global__ __launch_bounds__(256) void k_expand(const float* __restrict__ ws,
                                                float* __restrict__ y) {
    const int tid = threadIdx.x;
    const int oq  = blockIdx.x * 256 + tid;   // output quad 0..1023
    const int o0  = oq * 4;
    const int r0  = blockIdx.y * 32;

    const float4* partial = (const float4*)((const char*)ws + WS_PARTIAL_OFF);
    const float4* etab    = (const float4*)((const char*)ws + WS_E_OFF);
    const float4* btab    = (const float4*)((const char*)ws + WS_BIAS_OFF);

    float4 ew0 = etab[o0 + 0];
    float4 ew1 = etab[o0 + 1];
    float4 ew2 = etab[o0 + 2];
    float4 ew3 = etab[o0 + 3];
    float4 bq  = btab[oq];

    __shared__ float4 sp[32];
    if (tid < 32) {
        float4 p0 = partial[(r0 + tid) * 4 + 0];
        float4 p1 = partial[(r0 + tid) * 4 + 1];
        float4 p2 = partial[(r0 + tid) * 4 + 2];
        float4 p3 = partial[(r0 + tid) * 4 + 3];
        sp[tid] = make_float4(p0.x + p1.x + p2.x + p3.x,
                              p0.y + p1.y + p2.y + p3.y,
                              p0.z + p1.z + p2.z + p3.z,
                              p0.w + p1.w + p2.w + p3.w);
    }
    __syncthreads();

#pragma unroll 8
    for (int r = 0; r < 32; ++r) {
        const float4 tv = sp[r];
        float4 out;
        out.x = bq.x + ew0.x * tv.x + ew0.y * tv.y + ew0.z * tv.z + ew0.w * tv.w;
        out.y = bq.y + ew1.x * tv.x + ew1.y * tv.y + ew1.z * tv.z + ew1.w * tv.w;
        out.z = bq.z + ew2.x * tv.x + ew2.y * tv.y + ew2.z * tv.z + ew2.w * tv.w;
        out.w = bq.w + ew3.x * tv.x + ew3.y * tv.y + ew3.z * tv.z + ew3.w * tv.w;
        *(float4*)(y + (size_t)(r0 + r) * OUT_F + o0) = out;
    }
}

extern "C" void kernel_launch(void* const* d_in, const int* in_sizes, int n_in,
                              void* d_out, int out_size, void* d_ws, size_t ws_size,
                              hipStream_t stream) {
    const float* x   = (const float*)d_in[0];   // (16384, 4096) f32
    const float* cp  = (const float*)d_in[1];   // (4, 4) f32
    const float* bcp = (const float*)d_in[2];   // (4,) f32
    float* y  = (float*)d_out;
    float* ws = (float*)d_ws;

    k_init   <<<dim3(16),        dim3(256), 0, stream>>>(cp, bcp, ws);
    k_project<<<dim3(2048),      dim3(256), 0, stream>>>(x, ws);
    k_expand <<<dim3(4, 512),    dim3(256), 0, stream>>>(ws, y);
}